// Round 1
// baseline (495.298 us; speedup 1.0000x reference)
//
#include <hip/hip_runtime.h>
#include <math.h>

// Problem constants
#define B 32
#define N 4096
#define D 128
#define KTOP 512
#define NPB 2048
#define MSEG (B * NPB)      // 65536
#define E (B * N)           // 131072
#define MAXL 96             // max edges per segment (Poisson(2), max ~14)

// ---------------------------------------------------------------------------
// K0: per-batch precompute (fp64): query = cat(qh,qr,qt)@W_q+b_q,
// u_d = q_d*W1_d - W2_d + W3_d, v = W_a @ u, c2 = q.(W2+W3)+b_att+b_a.u
// ---------------------------------------------------------------------------
__global__ __launch_bounds__(128) void k0_precompute(
    const float* __restrict__ qh, const float* __restrict__ qr,
    const float* __restrict__ qt, const float* __restrict__ Wq,
    const float* __restrict__ bq, const float* __restrict__ Wa,
    const float* __restrict__ ba, const float* __restrict__ Watt,
    const float* __restrict__ batt, double* __restrict__ vws,
    double* __restrict__ c2ws) {
  int b = blockIdx.x, d = threadIdx.x;
  __shared__ double u[128];
  __shared__ double red[128];
  const float* qhb = qh + b * 128;
  const float* qrb = qr + b * 128;
  const float* qtb = qt + b * 128;
  double acc = (double)bq[d];
  for (int i = 0; i < 128; ++i) acc += (double)qhb[i] * (double)Wq[i * 128 + d];
  for (int i = 0; i < 128; ++i) acc += (double)qrb[i] * (double)Wq[(128 + i) * 128 + d];
  for (int i = 0; i < 128; ++i) acc += (double)qtb[i] * (double)Wq[(256 + i) * 128 + d];
  double w1 = (double)Watt[d], w2 = (double)Watt[128 + d], w3 = (double)Watt[256 + d];
  double ud = acc * w1 - w2 + w3;
  u[d] = ud;
  red[d] = acc * (w2 + w3) + (double)ba[d] * ud;
  __syncthreads();
  for (int s = 64; s > 0; s >>= 1) {
    if (d < s) red[d] += red[d + s];
    __syncthreads();
  }
  if (d == 0) c2ws[b] = red[0] + (double)batt[0];
  for (int i = d; i < 384; i += 128) {
    double vv = 0.0;
    for (int dd = 0; dd < 128; ++dd) vv += (double)Wa[i * 128 + dd] * u[dd];
    vws[b * 384 + i] = vv;
  }
}

// ---------------------------------------------------------------------------
// K1: per-edge attention. One wave (64 lanes) per edge.
// att[e] = 0.5*(sigmoid(r.v0 + t.v1 + time.v2 + c2_b) + sigmoid(h.Wrule + brule))
// ---------------------------------------------------------------------------
__global__ __launch_bounds__(256) void k1_att(
    const float* __restrict__ r, const float* __restrict__ t,
    const float* __restrict__ tm, const float* __restrict__ hidden,
    const float* __restrict__ Wrule, const float* __restrict__ brule,
    const double* __restrict__ vws, const double* __restrict__ c2ws,
    float* __restrict__ attw) {
  int wid = threadIdx.x >> 6;
  int lane = threadIdx.x & 63;
  int e = blockIdx.x * 4 + wid;
  int b = e >> 12;  // e / N
  size_t eo = (size_t)e * 128;
  const float2* r2 = (const float2*)(r + eo);
  const float2* t2 = (const float2*)(t + eo);
  const float2* m2 = (const float2*)(tm + eo);
  const float2* h2 = (const float2*)(hidden + eo);
  const double2* vb = (const double2*)(vws + b * 384);
  float2 ra = r2[lane], ta = t2[lane], ma = m2[lane], ha = h2[lane];
  double2 v0 = vb[lane], v1 = vb[64 + lane], v2 = vb[128 + lane];
  float2 wr = ((const float2*)Wrule)[lane];
  double p1 = (double)ra.x * v0.x + (double)ra.y * v0.y +
              (double)ta.x * v1.x + (double)ta.y * v1.y +
              (double)ma.x * v2.x + (double)ma.y * v2.y;
  double p2 = (double)ha.x * (double)wr.x + (double)ha.y * (double)wr.y;
  for (int off = 32; off > 0; off >>= 1) {
    p1 += __shfl_xor(p1, off);
    p2 += __shfl_xor(p2, off);
  }
  if (lane == 0) {
    double l1 = p1 + c2ws[b];
    double l2 = p2 + (double)brule[0];
    double a1 = 1.0 / (1.0 + exp(-l1));
    double a2 = 1.0 / (1.0 + exp(-l2));
    attw[e] = (float)(0.5 * (a1 + a2));
  }
}

// ---------------------------------------------------------------------------
// Counting sort: histogram, scan, scatter
// ---------------------------------------------------------------------------
__global__ __launch_bounds__(256) void k_hist(const int* __restrict__ tidx,
                                              int* __restrict__ counts) {
  int e = blockIdx.x * 256 + threadIdx.x;
  atomicAdd(&counts[tidx[e]], 1);
}

__global__ __launch_bounds__(256) void k_scanA(const int* __restrict__ counts,
                                               int* __restrict__ off,
                                               int* __restrict__ bsum) {
  __shared__ int sd[256];
  int tid = threadIdx.x;
  int g = blockIdx.x * 256 + tid;
  int c = counts[g];
  sd[tid] = c;
  __syncthreads();
  for (int s = 1; s < 256; s <<= 1) {
    int tv = (tid >= s) ? sd[tid - s] : 0;
    __syncthreads();
    sd[tid] += tv;
    __syncthreads();
  }
  off[g] = sd[tid] - c;
  if (tid == 255) bsum[blockIdx.x] = sd[255];
}

__global__ __launch_bounds__(256) void k_scanB(const int* __restrict__ bsum,
                                               int* __restrict__ boff) {
  __shared__ int sd[256];
  int tid = threadIdx.x;
  int c = bsum[tid];
  sd[tid] = c;
  __syncthreads();
  for (int s = 1; s < 256; s <<= 1) {
    int tv = (tid >= s) ? sd[tid - s] : 0;
    __syncthreads();
    sd[tid] += tv;
    __syncthreads();
  }
  boff[tid] = sd[tid] - c;
}

__global__ __launch_bounds__(256) void k_scanC(int* __restrict__ off,
                                               const int* __restrict__ boff,
                                               int* __restrict__ cur) {
  int g = blockIdx.x * 256 + threadIdx.x;
  int o = off[g] + boff[g >> 8];
  off[g] = o;
  cur[g] = o;
}

__global__ __launch_bounds__(256) void k_scatter(const int* __restrict__ tidx,
                                                 int* __restrict__ cur,
                                                 int* __restrict__ lists) {
  int e = blockIdx.x * 256 + threadIdx.x;
  int m = tidx[e];
  int pos = atomicAdd(&cur[m], 1);
  lists[pos] = e;
}

// ---------------------------------------------------------------------------
// K5: per-segment deterministic aggregation (ascending-e order, fp32 seq —
// matches np.add.at order). One 128-thread block per segment.
// ---------------------------------------------------------------------------
__global__ __launch_bounds__(128) void k5_agg(
    const float* __restrict__ r, const float* __restrict__ tm,
    const float* __restrict__ hidden, const float* __restrict__ qh,
    const float* __restrict__ tail_emd, const float* __restrict__ attw,
    const int* __restrict__ counts, const int* __restrict__ offs,
    const int* __restrict__ lists, float* __restrict__ tail_agg,
    float* __restrict__ new_hidden, float* __restrict__ agg_att) {
  int m = blockIdx.x;
  int d = threadIdx.x;
  int b = m >> 11;  // m / NPB
  __shared__ int s_list[MAXL];
  __shared__ float s_att[MAXL];
  int cnt = counts[m];
  if (cnt > MAXL) cnt = MAXL;
  int off = offs[m];
  if (d < cnt) s_list[d] = lists[off + d];
  __syncthreads();
  if (d == 0) {  // insertion sort -> ascending e
    for (int i = 1; i < cnt; i++) {
      int key = s_list[i];
      int j = i - 1;
      while (j >= 0 && s_list[j] > key) {
        s_list[j + 1] = s_list[j];
        j--;
      }
      s_list[j + 1] = key;
    }
  }
  __syncthreads();
  if (d < cnt) s_att[d] = attw[s_list[d]];
  __syncthreads();
  if (d == 0) {
    float s = 0.f;
    for (int j = 0; j < cnt; j++) s += s_att[j];
    agg_att[m] = s;
  }
  float qhd = qh[b * 128 + d];
  float accT = tail_emd[(size_t)m * 128 + d];
  float accH = 0.f;
  for (int j = 0; j < cnt; j++) {
    int e = s_list[j];
    float a = s_att[j];
    size_t eo = (size_t)e * 128 + d;
    float message = (qhd + r[eo]) + tm[eo];
    accT += a * message;
    accH += hidden[eo];
  }
  tail_agg[(size_t)m * 128 + d] = accT;
  new_hidden[(size_t)m * 128 + d] = accH;
}

// ---------------------------------------------------------------------------
// K6: per-batch exact top-K via full bitonic sort of 2048 (val desc, idx asc)
// ---------------------------------------------------------------------------
__global__ __launch_bounds__(1024) void k6_topk(
    const float* __restrict__ agg_att, const int* __restrict__ tail_nodes,
    float* __restrict__ out_nodes, int* __restrict__ idxw) {
  __shared__ float v[2048];
  __shared__ int ix[2048];
  int b = blockIdx.x, tid = threadIdx.x;
  for (int s = tid; s < 2048; s += 1024) {
    v[s] = agg_att[b * 2048 + s];
    ix[s] = s;
  }
  __syncthreads();
  for (int k = 2; k <= 2048; k <<= 1) {
    for (int j = k >> 1; j > 0; j >>= 1) {
      for (int t = tid; t < 2048; t += 1024) {
        int p = t ^ j;
        if (p > t) {
          bool asc = ((t & k) == 0);
          float vt = v[t], vp = v[p];
          int it = ix[t], ip = ix[p];
          // "p belongs before t" in desired order (desc val, asc idx on tie)
          bool before_p = (vp > vt) || (vp == vt && ip < it);
          if (before_p == asc) {
            v[t] = vp; v[p] = vt;
            ix[t] = ip; ix[p] = it;
          }
        }
      }
      __syncthreads();
    }
  }
  if (tid < KTOP) {
    int s = ix[tid];
    int gm = b * 2048 + s;
    out_nodes[(b * KTOP + tid) * 2 + 0] = (float)tail_nodes[gm * 3 + 1];
    out_nodes[(b * KTOP + tid) * 2 + 1] = (float)tail_nodes[gm * 3 + 2];
    idxw[b * KTOP + tid] = gm;
  }
}

// ---------------------------------------------------------------------------
// K7: gather + out_emd = emd @ W_out + b_out; hid = new_hidden[idx]
// 512 blocks x 32 rows. W_out staged in LDS (64 KB).
// ---------------------------------------------------------------------------
__global__ __launch_bounds__(256) void k7_out(
    const float* __restrict__ tail_agg, const float* __restrict__ new_hidden,
    const float* __restrict__ Wout, const float* __restrict__ bout,
    const int* __restrict__ idxw, float* __restrict__ out_emd,
    float* __restrict__ out_hid) {
  __shared__ float Ws[16384];
  __shared__ float es[256];
  int tid = threadIdx.x;
  int sub = tid >> 7, d = tid & 127;
  for (int i = tid; i < 16384; i += 256) Ws[i] = Wout[i];
  int base = blockIdx.x * 32;
  float bo = bout[d];
  for (int j = 0; j < 32; j += 2) {
    int row = base + j + sub;
    int m = idxw[row];
    __syncthreads();
    es[sub * 128 + d] = tail_agg[(size_t)m * 128 + d];
    __syncthreads();
    float acc = bo;
#pragma unroll 8
    for (int i = 0; i < 128; ++i) acc += es[sub * 128 + i] * Ws[i * 128 + d];
    out_emd[(size_t)row * 128 + d] = acc;
    out_hid[(size_t)row * 128 + d] = new_hidden[(size_t)m * 128 + d];
  }
}

// ---------------------------------------------------------------------------
extern "C" void kernel_launch(void* const* d_in, const int* in_sizes, int n_in,
                              void* d_out, int out_size, void* d_ws,
                              size_t ws_size, hipStream_t stream) {
  const float* q_head = (const float*)d_in[0];
  const float* q_rel = (const float*)d_in[1];
  const float* q_time = (const float*)d_in[2];
  const float* r_nb = (const float*)d_in[3];
  const float* t_nb = (const float*)d_in[4];
  const float* tm_nb = (const float*)d_in[5];
  const float* hidden = (const float*)d_in[6];
  const float* tail_emd = (const float*)d_in[7];
  const int* tail_index = (const int*)d_in[8];
  const int* tail_nodes = (const int*)d_in[9];
  const float* W_q = (const float*)d_in[10];
  const float* b_q = (const float*)d_in[11];
  const float* W_a = (const float*)d_in[12];
  const float* b_a = (const float*)d_in[13];
  const float* W_att = (const float*)d_in[14];
  const float* b_att = (const float*)d_in[15];
  const float* W_rule = (const float*)d_in[16];
  const float* b_rule = (const float*)d_in[17];
  const float* W_out = (const float*)d_in[18];
  const float* b_out = (const float*)d_in[19];

  char* ws = (char*)d_ws;
  double* vws = (double*)(ws + 0);            //  32*384*8 = 98304
  double* c2ws = (double*)(ws + 98304);       //  256
  float* attw = (float*)(ws + 98560);         //  E*4 = 524288
  int* counts = (int*)(ws + 622848);          //  M*4 = 262144
  int* offs = (int*)(ws + 884992);            //  262144
  int* cur = (int*)(ws + 1147136);            //  262144
  int* bsum = (int*)(ws + 1409280);           //  1024
  int* boff = (int*)(ws + 1410304);           //  1024
  int* lists = (int*)(ws + 1411328);          //  E*4 = 524288
  float* agg_att = (float*)(ws + 1935616);    //  M*4 = 262144
  int* idxw = (int*)(ws + 2197760);           //  B*K*4 = 65536
  float* tail_agg = (float*)(ws + 2263296);   //  M*128*4 = 33554432
  float* new_hid = (float*)(ws + 35817728);   //  33554432  (end 69372160)

  float* out_nodes = (float*)d_out;                      // B*K*2 floats
  float* out_emd = (float*)d_out + (size_t)B * KTOP * 2; // B*K*128
  float* out_hid = out_emd + (size_t)B * KTOP * 128;

  k0_precompute<<<B, 128, 0, stream>>>(q_head, q_rel, q_time, W_q, b_q, W_a,
                                       b_a, W_att, b_att, vws, c2ws);
  k1_att<<<E / 4, 256, 0, stream>>>(r_nb, t_nb, tm_nb, hidden, W_rule, b_rule,
                                    vws, c2ws, attw);
  hipMemsetAsync(counts, 0, MSEG * sizeof(int), stream);
  k_hist<<<E / 256, 256, 0, stream>>>(tail_index, counts);
  k_scanA<<<MSEG / 256, 256, 0, stream>>>(counts, offs, bsum);
  k_scanB<<<1, 256, 0, stream>>>(bsum, boff);
  k_scanC<<<MSEG / 256, 256, 0, stream>>>(offs, boff, cur);
  k_scatter<<<E / 256, 256, 0, stream>>>(tail_index, cur, lists);
  k5_agg<<<MSEG, 128, 0, stream>>>(r_nb, tm_nb, hidden, q_head, tail_emd, attw,
                                   counts, offs, lists, tail_agg, new_hid,
                                   agg_att);
  k6_topk<<<B, 1024, 0, stream>>>(agg_att, tail_nodes, out_nodes, idxw);
  k7_out<<<(B * KTOP) / 32, 256, 0, stream>>>(tail_agg, new_hid, W_out, b_out,
                                              idxw, out_emd, out_hid);
}